// Round 1
// baseline (330.080 us; speedup 1.0000x reference)
//
#include <hip/hip_runtime.h>

// Pipeline:
//  ws (d_ws) holds xt: [16][768][1156] fp32 = 56.8 MB
//  1) fill_borders_k : border patches (h1 or w1 in {0,33}) = bias[c1]
//  2) conv_gemm_k    : interior patches via fp32 tiled GEMM (+bias)
//  3) scan_k         : sequential 8-neighbor recurrence, one thread per (b,c1)
//  4) crop_k         : reinterpret as (16,3,544,544), crop [16:528] -> d_out

#define XT_PER_B (768 * 1156)   // 887808

__global__ __launch_bounds__(256) void fill_borders_k(const float* __restrict__ bias,
                                                      float* __restrict__ xt) {
    int tid = blockIdx.x * 256 + threadIdx.x;
    if (tid >= 16 * 768 * 132) return;
    int e  = tid % 132;
    int r  = tid / 132;
    int c1 = r % 768;
    int b  = r / 768;
    int pos;
    if (e < 34)       pos = e;                      // h1 == 0
    else if (e < 68)  pos = 1122 + (e - 34);        // h1 == 33
    else if (e < 100) pos = (e - 67) * 34;          // w1 == 0, h1 = 1..32
    else              pos = (e - 99) * 34 + 33;     // w1 == 33, h1 = 1..32
    xt[((size_t)b * 768 + c1) * 1156 + pos] = bias[c1];
}

// GEMM: C[m][n] = sum_k A[m][k]*W[n][k],  m=(b,ph,pw) patch, n=c1, k=(c,py,px)
__global__ __launch_bounds__(256) void conv_gemm_k(const float* __restrict__ x,
                                                   const float* __restrict__ w,
                                                   const float* __restrict__ bias,
                                                   float* __restrict__ xt) {
    __shared__ float As[32][68];   // [k][m], +4 pad keeps float4 rows aligned
    __shared__ float Ws[32][68];   // [k][n]
    const int m0 = blockIdx.x << 6;
    const int n0 = blockIdx.y << 6;
    const int tid = threadIdx.x;
    const int ty = tid >> 4, tx = tid & 15;
    float acc[4][4] = {{0.f, 0.f, 0.f, 0.f}, {0.f, 0.f, 0.f, 0.f},
                       {0.f, 0.f, 0.f, 0.f}, {0.f, 0.f, 0.f, 0.f}};

    for (int k0 = 0; k0 < 768; k0 += 32) {
        #pragma unroll
        for (int cc = 0; cc < 2; ++cc) {
            int chunk = tid + (cc << 8);
            int ml = chunk >> 3;          // 0..63 (row of tile)
            int k4 = (chunk & 7) << 2;    // 0,4,...,28
            int kk = k0 + k4;
            // A tile: x[b][c][ph*16+py][pw*16+px]
            int m  = m0 + ml;
            int bb = m >> 10, ph = (m >> 5) & 31, pw = m & 31;
            int ci = kk >> 8, py = (kk >> 4) & 15, px = kk & 15;
            int xoff = (((bb * 3 + ci) << 9) + (ph << 4) + py) * 512 + (pw << 4) + px;
            float4 va = *(const float4*)(x + xoff);
            As[k4 + 0][ml] = va.x; As[k4 + 1][ml] = va.y;
            As[k4 + 2][ml] = va.z; As[k4 + 3][ml] = va.w;
            // W tile: w[n][k] row-major, K stride 768
            float4 vw = *(const float4*)(w + (n0 + ml) * 768 + kk);
            Ws[k4 + 0][ml] = vw.x; Ws[k4 + 1][ml] = vw.y;
            Ws[k4 + 2][ml] = vw.z; Ws[k4 + 3][ml] = vw.w;
        }
        __syncthreads();
        #pragma unroll
        for (int k = 0; k < 32; ++k) {
            float4 a4 = *(const float4*)&As[k][ty << 2];
            float4 b4 = *(const float4*)&Ws[k][tx << 2];
            float av[4] = {a4.x, a4.y, a4.z, a4.w};
            float bv[4] = {b4.x, b4.y, b4.z, b4.w};
            #pragma unroll
            for (int e = 0; e < 4; ++e)
                #pragma unroll
                for (int f = 0; f < 4; ++f)
                    acc[e][f] = fmaf(av[e], bv[f], acc[e][f]);
        }
        __syncthreads();
    }
    #pragma unroll
    for (int e = 0; e < 4; ++e) {
        int m  = m0 + (ty << 2) + e;
        int bb = m >> 10, ph = (m >> 5) & 31, pw = m & 31;
        size_t base = (size_t)bb * XT_PER_B + (size_t)(ph + 1) * 34 + (pw + 1);
        #pragma unroll
        for (int f = 0; f < 4; ++f) {
            int n = n0 + (tx << 2) + f;
            xt[base + (size_t)n * 1156] = acc[e][f] + bias[n];
        }
    }
}

__device__ __forceinline__ void load33(float* R, const float* p) {
    #pragma unroll
    for (int q = 0; q < 8; ++q) {
        float4 v = *(const float4*)(p + q * 4);
        R[q * 4 + 0] = v.x; R[q * 4 + 1] = v.y;
        R[q * 4 + 2] = v.z; R[q * 4 + 3] = v.w;
    }
    R[32] = p[32];
}

__device__ __forceinline__ void storerow(float* p, float first, const float* cn) {
    *(float4*)(p) = make_float4(first, cn[1], cn[2], cn[3]);
    #pragma unroll
    for (int q = 1; q < 8; ++q)
        *(float4*)(p + q * 4) = make_float4(cn[q * 4 + 0], cn[q * 4 + 1],
                                            cn[q * 4 + 2], cn[q * 4 + 3]);
}

// One thread per (b, c1) chain. Sequential recurrence over i=1..30, j=1..31:
//   new[i][j] = (UL + U + UR + L + orig[idx+1] + orig[idx+31..33]) / 8
// UL/U/UR come from new row i-1 (when in the updated set), L from new[i][j-1].
__global__ __launch_bounds__(64) void scan_k(float* __restrict__ xt) {
    int t = blockIdx.x * 64 + threadIdx.x;     // 0..12287 = b*768 + c1
    float* p = xt + (size_t)t * 1156;
    float R0[33], R1[33], R2[33];              // orig rows i-1, i, i+1 (stride-32 rows)
    float pnv[32], cnv[32];                    // new row i-1, new row i (j=1..31)
    load33(R0, p);
    load33(R1, p + 32);
    load33(R2, p + 64);
    // i = 1: all up-neighbors are original (row 0)
    #pragma unroll
    for (int j = 1; j <= 31; ++j) {
        float L = (j >= 2) ? cnv[j - 1] : R1[0];
        float s = ((R0[j - 1] + R0[j]) + (R0[j + 1] + L))
                + ((R1[j + 1] + R2[j - 1]) + (R2[j] + R2[j + 1]));
        cnv[j] = s * 0.125f;
    }
    storerow(p + 32, R1[0], cnv);
    for (int i = 2; i <= 30; ++i) {
        float prev0 = R1[0];                   // orig[(i-1)*32]
        #pragma unroll
        for (int q = 0; q < 33; ++q) R1[q] = R2[q];
        load33(R2, p + (i + 1) * 32);
        #pragma unroll
        for (int j = 1; j <= 31; ++j) pnv[j] = cnv[j];
        #pragma unroll
        for (int j = 1; j <= 31; ++j) {
            float UL = (j >= 2)  ? pnv[j - 1] : prev0;     // orig[(i-1)*32] when j=1
            float U  = pnv[j];
            float UR = (j <= 30) ? pnv[j + 1] : R1[0];     // orig[(i-1)*32+32] = orig[i*32]
            float L  = (j >= 2)  ? cnv[j - 1] : R1[0];     // orig[i*32] when j=1
            float s = ((UL + U) + (UR + L))
                    + ((R1[j + 1] + R2[j - 1]) + (R2[j] + R2[j + 1]));
            cnv[j] = s * 0.125f;
        }
        storerow(p + i * 32, R1[0], cnv);
    }
}

// out[b][c][y][x] = xt_flat[b*887808 + c*295936 + (y+16)*544 + (x+16)]
__global__ __launch_bounds__(256) void crop_k(const float* __restrict__ xt,
                                              float* __restrict__ out) {
    int tid = blockIdx.x * 256 + threadIdx.x;  // one float4 each, 3145728 total
    int o  = tid << 2;                         // flat out index (b,c,y,x)
    int xx = o & 511;
    int y  = (o >> 9) & 511;
    int cb = o >> 18;                          // b*3 + c
    int c  = cb % 3;
    int b  = cb / 3;
    const float4 v = *(const float4*)(xt + (size_t)b * XT_PER_B + c * 295936
                                      + (y + 16) * 544 + (xx + 16));
    *(float4*)(out + o) = v;
}

extern "C" void kernel_launch(void* const* d_in, const int* in_sizes, int n_in,
                              void* d_out, int out_size, void* d_ws, size_t ws_size,
                              hipStream_t stream) {
    const float* x    = (const float*)d_in[0];
    const float* w    = (const float*)d_in[1];
    const float* bias = (const float*)d_in[2];
    float* out = (float*)d_out;
    float* xt  = (float*)d_ws;   // 16*768*1156 fp32 = 56,819,712 B

    fill_borders_k<<<6336, 256, 0, stream>>>(bias, xt);
    conv_gemm_k<<<dim3(256, 12), 256, 0, stream>>>(x, w, bias, xt);
    scan_k<<<192, 64, 0, stream>>>(xt);
    crop_k<<<12288, 256, 0, stream>>>(xt, out);
}

// Round 2
// 115.658 us; speedup vs baseline: 2.8539x; 2.8539x over previous
//
#include <hip/hip_runtime.h>
#include <hip/hip_bf16.h>

// Pipeline:
//  d_ws  : xt [16][768][1156] fp32 = 56.8 MB
//  d_out : reused as scratch for bf16 A (im2col'd x, [16384][768]) + bf16 W
//          ([768][768]); fully overwritten by crop_k at the end.
//  1) convert_x_k    : x fp32 -> A_bf16 [m=(b,ph,pw)][k=(c,py,px)]
//  2) convert_w_k    : w fp32 -> W_bf16 (already K-major)
//  3) fill_borders_k : border patches = bias[c1]
//  4) conv_gemm_mfma : 128x128 tile MFMA bf16 GEMM (+bias) -> xt interior
//  5) scan_k         : sequential 8-neighbor recurrence per (b,c1)
//  6) crop_k         : crop to d_out

#define XT_PER_B (768 * 1156)   // 887808

typedef __attribute__((ext_vector_type(8))) short s8v;     // 8 bf16 (4 VGPRs)
typedef __attribute__((ext_vector_type(4))) float f4v;     // MFMA acc
typedef __attribute__((ext_vector_type(8))) unsigned short us8;

__device__ __forceinline__ unsigned short f2bf(float f) {
    __hip_bfloat16 h = __float2bfloat16(f);
    return *reinterpret_cast<unsigned short*>(&h);
}

__device__ __forceinline__ void gload_lds16(const void* g, void* l) {
    __builtin_amdgcn_global_load_lds(
        (const __attribute__((address_space(1))) unsigned int*)g,
        (__attribute__((address_space(3))) unsigned int*)l,
        16, 0, 0);
}

// x [16][3][512][512] f32 -> A_bf [16384][768] bf16, A[m][k], m=(b,ph,pw), k=(c,py,px)
__global__ __launch_bounds__(256) void convert_x_k(const float* __restrict__ x,
                                                   unsigned short* __restrict__ a) {
    int g = blockIdx.x * 256 + threadIdx.x;    // 1,572,864 threads, 8 floats each
    int f = g << 3;
    int wc = f & 511;
    int h  = (f >> 9) & 511;
    int cb = f >> 18;                          // b*3 + c
    int c  = cb % 3, b = cb / 3;
    const float4 v0 = *(const float4*)(x + f);
    const float4 v1 = *(const float4*)(x + f + 4);
    int m = (b << 10) + ((h >> 4) << 5) + (wc >> 4);
    int k = (c << 8) + ((h & 15) << 4) + (wc & 15);
    us8 o;
    o[0] = f2bf(v0.x); o[1] = f2bf(v0.y); o[2] = f2bf(v0.z); o[3] = f2bf(v0.w);
    o[4] = f2bf(v1.x); o[5] = f2bf(v1.y); o[6] = f2bf(v1.z); o[7] = f2bf(v1.w);
    *(us8*)(a + (size_t)m * 768 + k) = o;
}

// w [768][768] f32 (row-major, K contiguous) -> bf16, same layout
__global__ __launch_bounds__(256) void convert_w_k(const float* __restrict__ w,
                                                   unsigned short* __restrict__ o) {
    int g = blockIdx.x * 256 + threadIdx.x;    // 73,728 threads
    int f = g << 3;
    const float4 v0 = *(const float4*)(w + f);
    const float4 v1 = *(const float4*)(w + f + 4);
    us8 u;
    u[0] = f2bf(v0.x); u[1] = f2bf(v0.y); u[2] = f2bf(v0.z); u[3] = f2bf(v0.w);
    u[4] = f2bf(v1.x); u[5] = f2bf(v1.y); u[6] = f2bf(v1.z); u[7] = f2bf(v1.w);
    *(us8*)(o + f) = u;
}

__global__ __launch_bounds__(256) void fill_borders_k(const float* __restrict__ bias,
                                                      float* __restrict__ xt) {
    int tid = blockIdx.x * 256 + threadIdx.x;
    if (tid >= 16 * 768 * 132) return;
    int e  = tid % 132;
    int r  = tid / 132;
    int c1 = r % 768;
    int b  = r / 768;
    int pos;
    if (e < 34)       pos = e;                      // h1 == 0
    else if (e < 68)  pos = 1122 + (e - 34);        // h1 == 33
    else if (e < 100) pos = (e - 67) * 34;          // w1 == 0, h1 = 1..32
    else              pos = (e - 99) * 34 + 33;     // w1 == 33, h1 = 1..32
    xt[((size_t)b * 768 + c1) * 1156 + pos] = bias[c1];
}

// C[m][n] = sum_k A[m][k] * W[n][k]; 128x128 tile, BK=32, 4 waves (2x2 of 64x64)
__global__ __launch_bounds__(256) void conv_gemm_mfma_k(const unsigned short* __restrict__ A,
                                                        const unsigned short* __restrict__ W,
                                                        const float* __restrict__ bias,
                                                        float* __restrict__ xt) {
    __shared__ __align__(16) unsigned short As[128 * 32];   // [row][k] linear, 8 KB
    __shared__ __align__(16) unsigned short Bs[128 * 32];
    const int tid  = threadIdx.x;
    const int lane = tid & 63, wv = tid >> 6;
    const int wr = wv >> 1, wc = wv & 1;
    const int m0 = blockIdx.x << 7, n0 = blockIdx.y << 7;

    f4v acc[4][4] = {};

    // staging addresses: wave wv covers tile rows [wv*32, wv*32+32)
    const unsigned short* gA = A + (size_t)(m0 + (wv << 5) + (lane >> 2)) * 768 + ((lane & 3) << 3);
    const unsigned short* gB = W + (size_t)(n0 + (wv << 5) + (lane >> 2)) * 768 + ((lane & 3) << 3);
    unsigned short* lA = As + (wv << 10);   // 1024 elems = 2 KB per wave
    unsigned short* lB = Bs + (wv << 10);

    for (int k0 = 0; k0 < 768; k0 += 32) {
        gload_lds16(gA + k0,            lA);
        gload_lds16(gA + k0 + 16 * 768, lA + 512);
        gload_lds16(gB + k0,            lB);
        gload_lds16(gB + k0 + 16 * 768, lB + 512);
        __syncthreads();
        s8v a[4], b[4];
        #pragma unroll
        for (int mi = 0; mi < 4; ++mi)
            a[mi] = *(const s8v*)(As + (((wr << 6) + (mi << 4) + (lane & 15)) << 5) + ((lane >> 4) << 3));
        #pragma unroll
        for (int ni = 0; ni < 4; ++ni)
            b[ni] = *(const s8v*)(Bs + (((wc << 6) + (ni << 4) + (lane & 15)) << 5) + ((lane >> 4) << 3));
        #pragma unroll
        for (int mi = 0; mi < 4; ++mi)
            #pragma unroll
            for (int ni = 0; ni < 4; ++ni)
                acc[mi][ni] = __builtin_amdgcn_mfma_f32_16x16x32_bf16(a[mi], b[ni], acc[mi][ni], 0, 0, 0);
        __syncthreads();
    }

    #pragma unroll
    for (int ni = 0; ni < 4; ++ni) {
        int n = n0 + (wc << 6) + (ni << 4) + (lane & 15);
        float bv = bias[n];
        #pragma unroll
        for (int mi = 0; mi < 4; ++mi) {
            #pragma unroll
            for (int r = 0; r < 4; ++r) {
                int m  = m0 + (wr << 6) + (mi << 4) + ((lane >> 4) << 2) + r;
                int bb = m >> 10, ph = (m >> 5) & 31, pw = m & 31;
                xt[(size_t)bb * XT_PER_B + (size_t)n * 1156 + (ph + 1) * 34 + (pw + 1)]
                    = acc[mi][ni][r] + bv;
            }
        }
    }
}

__device__ __forceinline__ void load33(float* R, const float* p) {
    #pragma unroll
    for (int q = 0; q < 8; ++q) {
        float4 v = *(const float4*)(p + q * 4);
        R[q * 4 + 0] = v.x; R[q * 4 + 1] = v.y;
        R[q * 4 + 2] = v.z; R[q * 4 + 3] = v.w;
    }
    R[32] = p[32];
}

__device__ __forceinline__ void storerow(float* p, float first, const float* cn) {
    *(float4*)(p) = make_float4(first, cn[1], cn[2], cn[3]);
    #pragma unroll
    for (int q = 1; q < 8; ++q)
        *(float4*)(p + q * 4) = make_float4(cn[q * 4 + 0], cn[q * 4 + 1],
                                            cn[q * 4 + 2], cn[q * 4 + 3]);
}

// One thread per (b, c1) chain; faithful stride-32 indexing into the 34-wide grid.
__global__ __launch_bounds__(64) void scan_k(float* __restrict__ xt) {
    int t = blockIdx.x * 64 + threadIdx.x;     // b*768 + c1
    float* p = xt + (size_t)t * 1156;
    float R0[33], R1[33], R2[33];
    float pnv[32], cnv[32];
    load33(R0, p);
    load33(R1, p + 32);
    load33(R2, p + 64);
    #pragma unroll
    for (int j = 1; j <= 31; ++j) {
        float L = (j >= 2) ? cnv[j - 1] : R1[0];
        float s = ((R0[j - 1] + R0[j]) + (R0[j + 1] + L))
                + ((R1[j + 1] + R2[j - 1]) + (R2[j] + R2[j + 1]));
        cnv[j] = s * 0.125f;
    }
    storerow(p + 32, R1[0], cnv);
    for (int i = 2; i <= 30; ++i) {
        float prev0 = R1[0];
        #pragma unroll
        for (int q = 0; q < 33; ++q) R1[q] = R2[q];
        load33(R2, p + (i + 1) * 32);
        #pragma unroll
        for (int j = 1; j <= 31; ++j) pnv[j] = cnv[j];
        #pragma unroll
        for (int j = 1; j <= 31; ++j) {
            float UL = (j >= 2)  ? pnv[j - 1] : prev0;
            float U  = pnv[j];
            float UR = (j <= 30) ? pnv[j + 1] : R1[0];
            float L  = (j >= 2)  ? cnv[j - 1] : R1[0];
            float s = ((UL + U) + (UR + L))
                    + ((R1[j + 1] + R2[j - 1]) + (R2[j] + R2[j + 1]));
            cnv[j] = s * 0.125f;
        }
        storerow(p + i * 32, R1[0], cnv);
    }
}

__global__ __launch_bounds__(256) void crop_k(const float* __restrict__ xt,
                                              float* __restrict__ out) {
    int tid = blockIdx.x * 256 + threadIdx.x;
    int o  = tid << 2;
    int xx = o & 511;
    int y  = (o >> 9) & 511;
    int cb = o >> 18;
    int c  = cb % 3;
    int b  = cb / 3;
    const float4 v = *(const float4*)(xt + (size_t)b * XT_PER_B + c * 295936
                                      + (y + 16) * 544 + (xx + 16));
    *(float4*)(out + o) = v;
}

extern "C" void kernel_launch(void* const* d_in, const int* in_sizes, int n_in,
                              void* d_out, int out_size, void* d_ws, size_t ws_size,
                              hipStream_t stream) {
    const float* x    = (const float*)d_in[0];
    const float* w    = (const float*)d_in[1];
    const float* bias = (const float*)d_in[2];
    float* out = (float*)d_out;
    float* xt  = (float*)d_ws;   // 56.8 MB

    // scratch inside d_out (50.3 MB): A_bf16 (25.2 MB) + W_bf16 (1.18 MB)
    unsigned short* a_bf = (unsigned short*)d_out;
    unsigned short* w_bf = a_bf + (size_t)16384 * 768;

    convert_x_k<<<6144, 256, 0, stream>>>(x, a_bf);
    convert_w_k<<<288, 256, 0, stream>>>(w, w_bf);
    fill_borders_k<<<6336, 256, 0, stream>>>(bias, xt);
    conv_gemm_mfma_k<<<dim3(128, 6), 256, 0, stream>>>(a_bf, w_bf, bias, xt);
    scan_k<<<192, 64, 0, stream>>>(xt);
    crop_k<<<12288, 256, 0, stream>>>(xt, out);
}